// Round 1
// baseline (1073.825 us; speedup 1.0000x reference)
//
#include <hip/hip_runtime.h>
#include <math.h>

#define NUM_K 19
#define CDIM 512
#define BDIM 8
#define HWDIM 16384   // 128*128
#define NPLANES 38    // planes 0..18: features_s, 19..37: features_t

// ---------------------------------------------------------------------------
// Kernel 1: per-class channel sums.
// One wave per (b,c) row (4096 rows), 4 waves per 256-thread block.
// LDS accumulator layout acc[class_plane][tid]: bank = tid&31 regardless of
// label -> every ds_add_f32 is exactly 2-way bank aliased (free, m136).
// atomicAdd on thread-private LDS slots => non-returning ds_add_f32, one LDS
// op per element. No __syncthreads needed: each thread touches only its own
// column.
// ---------------------------------------------------------------------------
__global__ __launch_bounds__(256)
void class_sum_kernel(const float* __restrict__ fs, const float* __restrict__ ft,
                      const int* __restrict__ lab,
                      float* __restrict__ Ss, float* __restrict__ St) {
    __shared__ float acc[NPLANES][256];
    const int tid = threadIdx.x;
#pragma unroll
    for (int k = 0; k < NPLANES; ++k) acc[k][tid] = 0.0f;

    const int wv = tid >> 6;
    const int lane = tid & 63;
    const int row = (blockIdx.x << 2) + wv;      // 0..4095 == b*512 + c
    const int b = row >> 9;
    const int c = row & 511;

    const float* ps = fs + ((size_t)row << 14);  // row * 16384
    const float* pt = ft + ((size_t)row << 14);
    const int*   pl = lab + ((size_t)b << 14);

#pragma unroll 4
    for (int it = 0; it < 64; ++it) {
        const int idx = (it << 8) + (lane << 2);           // float4 coalesced
        const float4 vs = *(const float4*)(ps + idx);
        const float4 vt = *(const float4*)(pt + idx);
        const int4   l4 = *(const int4*)(pl + idx);
        atomicAdd(&acc[l4.x][tid], vs.x);
        atomicAdd(&acc[l4.y][tid], vs.y);
        atomicAdd(&acc[l4.z][tid], vs.z);
        atomicAdd(&acc[l4.w][tid], vs.w);
        atomicAdd(&acc[NUM_K + l4.x][tid], vt.x);
        atomicAdd(&acc[NUM_K + l4.y][tid], vt.y);
        atomicAdd(&acc[NUM_K + l4.z][tid], vt.z);
        atomicAdd(&acc[NUM_K + l4.w][tid], vt.w);
    }

    // Wave-level reduction: each thread reads only its own column, then
    // shuffle-reduce across the 64 lanes that share this (b,c) row.
    for (int k = 0; k < NUM_K; ++k) {
        float v = acc[k][tid];
        float w = acc[NUM_K + k][tid];
#pragma unroll
        for (int off = 32; off > 0; off >>= 1) {
            v += __shfl_down(v, off, 64);
            w += __shfl_down(w, off, 64);
        }
        if (lane == 0) {
            atomicAdd(&Ss[k * CDIM + c], v);
            atomicAdd(&St[k * CDIM + c], w);
        }
    }
}

// ---------------------------------------------------------------------------
// Kernel 2: per-class pixel counts (tiny: 131072 labels).
// ---------------------------------------------------------------------------
__global__ __launch_bounds__(256)
void count_kernel(const int* __restrict__ lab, float* __restrict__ counts) {
    __shared__ int h[NUM_K];
    const int tid = threadIdx.x;
    if (tid < NUM_K) h[tid] = 0;
    __syncthreads();
    const int i = blockIdx.x * 256 + tid;      // one int4 per thread
    const int4 l4 = ((const int4*)lab)[i];
    atomicAdd(&h[l4.x], 1);
    atomicAdd(&h[l4.y], 1);
    atomicAdd(&h[l4.z], 1);
    atomicAdd(&h[l4.w], 1);
    __syncthreads();
    if (tid < NUM_K) atomicAdd(&counts[tid], (float)h[tid]);
}

// ---------------------------------------------------------------------------
// Kernel 3: normalize, 19x19 logits, masked logsumexp loss. One block.
// ---------------------------------------------------------------------------
__global__ __launch_bounds__(1024)
void finalize_kernel(const float* __restrict__ Ss, const float* __restrict__ St,
                     const float* __restrict__ counts, float* __restrict__ out) {
    __shared__ float ms[NUM_K][CDIM];
    __shared__ float mt[NUM_K][CDIM];
    __shared__ float scs[NUM_K], sct[NUM_K], cnt[NUM_K], invd[NUM_K];
    __shared__ float logits[NUM_K][NUM_K];
    const int tid = threadIdx.x;
    if (tid < NUM_K) {
        const float cv = counts[tid];
        cnt[tid] = cv;
        invd[tid] = 1.0f / fmaxf(cv, 1.0f);
    }
    __syncthreads();

    float* msf = &ms[0][0];
    float* mtf = &mt[0][0];
    for (int i = tid; i < NUM_K * CDIM; i += 1024) {
        const float id = invd[i >> 9];
        msf[i] = Ss[i] * id;
        mtf[i] = St[i] * id;
    }
    __syncthreads();

    const int wv = tid >> 6, lane = tid & 63;
    // Row L2 norms -> scale factors (normalization folded into logits).
    for (int k = wv; k < NUM_K; k += 16) {
        const float4* rs = (const float4*)&ms[k][0];
        const float4* rt = (const float4*)&mt[k][0];
        const float4 a0 = rs[lane * 2], a1 = rs[lane * 2 + 1];
        const float4 b0 = rt[lane * 2], b1 = rt[lane * 2 + 1];
        float ssum = a0.x*a0.x + a0.y*a0.y + a0.z*a0.z + a0.w*a0.w
                   + a1.x*a1.x + a1.y*a1.y + a1.z*a1.z + a1.w*a1.w;
        float tsum = b0.x*b0.x + b0.y*b0.y + b0.z*b0.z + b0.w*b0.w
                   + b1.x*b1.x + b1.y*b1.y + b1.z*b1.z + b1.w*b1.w;
#pragma unroll
        for (int off = 32; off > 0; off >>= 1) {
            ssum += __shfl_down(ssum, off, 64);
            tsum += __shfl_down(tsum, off, 64);
        }
        if (lane == 0) {
            scs[k] = 1.0f / fmaxf(sqrtf(ssum), 1e-12f);
            sct[k] = 1.0f / fmaxf(sqrtf(tsum), 1e-12f);
        }
    }
    __syncthreads();

    // logits[i][j] = (norm_s[i] . norm_t[j]) / TEMP
    for (int i = wv; i < NUM_K; i += 16) {
        const float4* rs = (const float4*)&ms[i][0];
        const float4 a0 = rs[lane * 2], a1 = rs[lane * 2 + 1];
        for (int j = 0; j < NUM_K; ++j) {
            const float4* rt = (const float4*)&mt[j][0];
            const float4 b0 = rt[lane * 2], b1 = rt[lane * 2 + 1];
            float d = a0.x*b0.x + a0.y*b0.y + a0.z*b0.z + a0.w*b0.w
                    + a1.x*b1.x + a1.y*b1.y + a1.z*b1.z + a1.w*b1.w;
#pragma unroll
            for (int off = 32; off > 0; off >>= 1) d += __shfl_down(d, off, 64);
            if (lane == 0) logits[i][j] = d * scs[i] * sct[j] * 10.0f;
        }
    }
    __syncthreads();

    if (wv == 0) {
        float val = 0.0f, pres = 0.0f;
        if (lane < NUM_K) {
            float m = -3.0e38f;
            for (int j = 0; j < NUM_K; ++j) m = fmaxf(m, logits[lane][j]);
            float s = 0.0f;
            for (int j = 0; j < NUM_K; ++j) s += expf(logits[lane][j] - m);
            const float lse = m + logf(s);
            if (cnt[lane] > 0.0f) { val = logits[lane][lane] - lse; pres = 1.0f; }
        }
#pragma unroll
        for (int off = 32; off > 0; off >>= 1) {
            val += __shfl_down(val, off, 64);
            pres += __shfl_down(pres, off, 64);
        }
        if (lane == 0) out[0] = -val / pres;
    }
}

extern "C" void kernel_launch(void* const* d_in, const int* in_sizes, int n_in,
                              void* d_out, int out_size, void* d_ws, size_t ws_size,
                              hipStream_t stream) {
    const float* fs = (const float*)d_in[0];
    const float* ft = (const float*)d_in[1];
    const int* lab = (const int*)d_in[2];

    float* Ss = (float*)d_ws;                    // 19*512 floats
    float* St = Ss + NUM_K * CDIM;               // 19*512 floats
    float* counts = St + NUM_K * CDIM;           // 19 floats

    hipMemsetAsync(d_ws, 0, (size_t)(2 * NUM_K * CDIM + NUM_K) * sizeof(float), stream);

    hipLaunchKernelGGL(count_kernel, dim3(131072 / 4 / 256), dim3(256), 0, stream,
                       lab, counts);
    hipLaunchKernelGGL(class_sum_kernel, dim3(4096 / 4), dim3(256), 0, stream,
                       fs, ft, lab, Ss, St);
    hipLaunchKernelGGL(finalize_kernel, dim3(1), dim3(1024), 0, stream,
                       Ss, St, counts, (float*)d_out);
}